// Round 10
// baseline (1483.290 us; speedup 1.0000x reference)
//
#include <hip/hip_runtime.h>
#include <hip/hip_cooperative_groups.h>
#include <math.h>

namespace cg = cooperative_groups;

// ---------------------------------------------------------------------------
// Sizes (fixed by the reference)
// ---------------------------------------------------------------------------
#define N_NODES 2048
#define N_EDGES 4096
#define L_DIM   4096
#define NBLK    1024                // cooperative grid: 4 blocks/CU co-resident
#define ROWS1   76                  // DIN rows per block (1024*76 = 77824)
#define NCHUNK2 256
#define ROWS2   4

typedef float v4f __attribute__((ext_vector_type(4)));
__device__ __forceinline__ float4 ntload4(const float4* p) {
    v4f v = __builtin_nontemporal_load((const v4f*)p);
    float4 r; r.x = v.x; r.y = v.y; r.z = v.z; r.w = v.w;
    return r;
}
__device__ __forceinline__ float dot4(float4 a, float4 b) {
    return a.x * b.x + a.y * b.y + a.z * b.z + a.w * b.w;
}
__device__ __forceinline__ float wred(float v) {   // 64-lane butterfly sum
    v += __shfl_xor(v, 1);  v += __shfl_xor(v, 2);  v += __shfl_xor(v, 4);
    v += __shfl_xor(v, 8);  v += __shfl_xor(v, 16); v += __shfl_xor(v, 32);
    return v;
}

struct KP {
    const float *X, *Z, *adj_e, *adj_v, *T, *cost, *flag, *dual;
    const float *W1, *b1, *W2, *b2, *Wm1, *bm1, *Wm2, *bm2, *Wm3, *bm3;
    float *out;
    float *Ze, *P1, *P2, *emb; int *src; float *lse;
    float *part1, *part2, *h2;
};

// ===========================================================================
// PATH 1: whole pipeline in one cooperative kernel (8 phases, 7 grid syncs)
// ===========================================================================
__global__ __launch_bounds__(256, 4) void fused_all(KP P) {
    cg::grid_group grid = cg::this_grid();
    const int tid  = threadIdx.x;
    const int bid  = blockIdx.x;
    const int lane = tid & 63, wid = tid >> 6;

    __shared__ float sred[4][4];
    __shared__ float stze[2];
    __shared__ int   si[256];
    __shared__ float scratch[256];      // reused: prep-sf / F / G / H
    __shared__ float wsl[4][16];
    __shared__ float hsC[2][16];
    __shared__ float hsvF[4];
    __shared__ float xsE[128];
    __shared__ float xvE[128];
    __shared__ int   riE[128];
    __shared__ int   wcE[2];
    __shared__ int   cntE;

    // ============ Phase A: Ze = adj_e @ Z (4 rows/block) + prep (block 0) ==
    {
        const int r0 = bid * 4;
        const float4* Z4 = (const float4*)P.Z;
        const float4* A0 = (const float4*)P.adj_e + (size_t)r0 * 1024;
        float a0 = 0.f, a1 = 0.f, a2 = 0.f, a3 = 0.f;
        #pragma unroll
        for (int q = 0; q < 4; ++q) {
            const int p = tid + q * 256;
            float4 zv = Z4[p];
            a0 += dot4(ntload4(A0 + p), zv);
            a1 += dot4(ntload4(A0 + 1024 + p), zv);
            a2 += dot4(ntload4(A0 + 2048 + p), zv);
            a3 += dot4(ntload4(A0 + 3072 + p), zv);
        }
        a0 = wred(a0); a1 = wred(a1); a2 = wred(a2); a3 = wred(a3);
        if (lane == 0) { sred[wid][0] = a0; sred[wid][1] = a1;
                         sred[wid][2] = a2; sred[wid][3] = a3; }
        __syncthreads();
        if (tid < 4)
            P.Ze[r0 + tid] = sred[0][tid] + sred[1][tid] + sred[2][tid] + sred[3][tid];

        if (bid == 0) {
            const int base = tid * 16;
            const float4* F4 = (const float4*)P.flag;
            float fv[16];
            #pragma unroll
            for (int q = 0; q < 4; ++q) {
                float4 v = F4[tid * 4 + q];
                fv[q*4+0] = v.x; fv[q*4+1] = v.y; fv[q*4+2] = v.z; fv[q*4+3] = v.w;
            }
            int f[16]; int local = 0;
            #pragma unroll
            for (int e = 0; e < 16; ++e) { f[e] = fv[e] > 0.5f ? 1 : 0; local += f[e]; }
            si[tid] = local;
            __syncthreads();
            #pragma unroll
            for (int off = 1; off < 256; off <<= 1) {
                int t = si[tid];
                if (tid >= off) t += si[tid - off];
                __syncthreads();
                si[tid] = t;
                __syncthreads();
            }
            int run = si[tid] - local;
            #pragma unroll
            for (int e = 0; e < 16; ++e) {
                run += f[e];
                int v = run - 1;
                v = v < 0 ? 0 : (v > N_NODES - 1 ? N_NODES - 1 : v);
                P.src[base + e] = v;
            }
            const float4* C4v = (const float4*)P.cost;
            float4 cv = C4v[tid*4+0], cw = C4v[tid*4+1];
            float4 cy = C4v[tid*4+2], cz = C4v[tid*4+3];
            float m = fmaxf(fmaxf(fmaxf(cv.x,cv.y), fmaxf(cv.z,cv.w)),
                            fmaxf(fmaxf(cw.x,cw.y), fmaxf(cw.z,cw.w)));
            m = fmaxf(m, fmaxf(fmaxf(fmaxf(cy.x,cy.y), fmaxf(cy.z,cy.w)),
                               fmaxf(fmaxf(cz.x,cz.y), fmaxf(cz.z,cz.w))));
            scratch[tid] = m;
            __syncthreads();
            for (int off = 128; off > 0; off >>= 1) {
                if (tid < off) scratch[tid] = fmaxf(scratch[tid], scratch[tid + off]);
                __syncthreads();
            }
            const float M = scratch[0];
            __syncthreads();
            float sum = expf(cv.x-M)+expf(cv.y-M)+expf(cv.z-M)+expf(cv.w-M)
                      + expf(cw.x-M)+expf(cw.y-M)+expf(cw.z-M)+expf(cw.w-M)
                      + expf(cy.x-M)+expf(cy.y-M)+expf(cy.z-M)+expf(cy.w-M)
                      + expf(cz.x-M)+expf(cz.y-M)+expf(cz.z-M)+expf(cz.w-M);
            scratch[tid] = sum;
            __syncthreads();
            for (int off = 128; off > 0; off >>= 1) {
                if (tid < off) scratch[tid] += scratch[tid + off];
                __syncthreads();
            }
            if (tid == 0) P.lse[0] = M + logf(scratch[0]);
        }
    }
    grid.sync();

    // ============ Phase B: tze = T @ Ze (2 rows/block); P1 tile ============
    const int rB = bid * 2;
    {
        const float4* Ze4 = (const float4*)P.Ze;
        const float4* T0  = (const float4*)P.T + (size_t)rB * 1024;
        float a0 = 0.f, a1 = 0.f;
        #pragma unroll
        for (int q = 0; q < 4; ++q) {
            const int p = tid + q * 256;
            float4 zv = Ze4[p];
            a0 += dot4(ntload4(T0 + p), zv);
            a1 += dot4(ntload4(T0 + 1024 + p), zv);
        }
        a0 = wred(a0); a1 = wred(a1);
        if (lane == 0) { sred[wid][0] = a0; sred[wid][1] = a1; }
        __syncthreads();
        if (tid < 2) stze[tid] = sred[0][tid] + sred[1][tid] + sred[2][tid] + sred[3][tid];
        __syncthreads();
        if (tid < 32) {
            const int rr = tid >> 4, c = tid & 15;
            const int row = rB + rr;
            P.P1[(row >> 2) * 64 + c * 4 + (row & 3)] =
                P.X[row] * P.W1[c] + stze[rr] * P.W1[16 + c];
        }
    }
    grid.sync();

    // ============ Phase C: Hh = relu(adj_v@P1 + b1); P2 = Hh@W2 ============
    {
        const int row = tid >> 7, p = tid & 127;     // 2 rows x 128 k-lanes
        const int r = rB + row;
        const float4* Av  = (const float4*)P.adj_v + (size_t)r * 512;
        const float4* P1v = (const float4*)P.P1;
        float acc[16];
        #pragma unroll
        for (int c = 0; c < 16; ++c) acc[c] = 0.f;
        #pragma unroll
        for (int it = 0; it < 4; ++it) {
            const int k4 = it * 128 + p;
            float4 a = ntload4(Av + k4);
            const float4* Pr = P1v + (size_t)k4 * 16;
            #pragma unroll
            for (int c = 0; c < 16; ++c) {
                float4 pv = Pr[c];
                acc[c] += dot4(a, pv);
            }
        }
        #pragma unroll
        for (int c = 0; c < 16; ++c) {
            float v = wred(acc[c]);
            if (lane == 0) wsl[wid][c] = v;
        }
        __syncthreads();
        if (tid < 32) {
            const int rr = tid >> 4, c = tid & 15;
            hsC[rr][c] = fmaxf(wsl[2*rr][c] + wsl[2*rr+1][c] + P.b1[c], 0.f);
        }
        __syncthreads();
        if (tid < 32) {
            const int rr = tid >> 4, c2 = tid & 15;
            float sv = 0.f;
            #pragma unroll
            for (int h = 0; h < 16; ++h) sv += hsC[rr][h] * P.W2[h * 16 + c2];
            const int k = rB + rr;
            P.P2[(k >> 2) * 64 + c2 * 4 + (k & 3)] = sv;
        }
    }
    grid.sync();

    // ============ Phase D: emb = adj_v@P2 + b2  (row-major out) ============
    {
        const int row = tid >> 7, p = tid & 127;
        const int r = rB + row;
        const float4* Av  = (const float4*)P.adj_v + (size_t)r * 512;
        const float4* P2v = (const float4*)P.P2;
        float acc[16];
        #pragma unroll
        for (int c = 0; c < 16; ++c) acc[c] = 0.f;
        #pragma unroll
        for (int it = 0; it < 4; ++it) {
            const int k4 = it * 128 + p;
            float4 a = ntload4(Av + k4);
            const float4* Pr = P2v + (size_t)k4 * 16;
            #pragma unroll
            for (int c = 0; c < 16; ++c) {
                float4 pv = Pr[c];
                acc[c] += dot4(a, pv);
            }
        }
        #pragma unroll
        for (int c = 0; c < 16; ++c) {
            float v = wred(acc[c]);
            if (lane == 0) wsl[wid][c] = v;
        }
        __syncthreads();
        if (tid < 32) {
            const int rr = tid >> 4, c = tid & 15;
            P.emb[(rB + rr) * 16 + c] = wsl[2*rr][c] + wsl[2*rr+1][c] + P.b2[c];
        }
    }
    grid.sync();

    // ============ Phase E: obs (on the fly) @ Wm1 -> part1[bid][:] =========
    {
        const int row0 = bid * ROWS1;
        if (tid < ROWS1) {
            const int i_din = row0 + tid;
            const int i = i_din / 19;
            const int c = i_din - i * 19;
            const float fl = P.flag[i];
            float v;
            if (c == 0)      v = P.cost[i] - P.lse[0];
            else if (c == 1) v = fl;
            else if (c == 2) v = (fl > 0.5f) ? P.dual[P.src[i]] : 1.0f;
            else             v = (fl > 0.5f) ? P.emb[P.src[i] * 16 + (c - 3)] : 0.0f;
            xsE[tid] = v;
        }
        __syncthreads();
        const bool pred = (tid < ROWS1) && (xsE[tid] != 0.0f);
        const unsigned long long mask = __ballot(pred);
        const int wpre = __popcll(mask & ((1ull << lane) - 1ull));
        if (lane == 0 && wid < 2) wcE[wid] = __popcll(mask);
        __syncthreads();
        if (tid == 0) cntE = wcE[0] + wcE[1];
        __syncthreads();
        if (pred) {
            const int idx = (wid == 0 ? 0 : wcE[0]) + wpre;
            xvE[idx] = xsE[tid];
            riE[idx] = tid;
        }
        __syncthreads();
        const int cnt = cntE;
        const float4* W4 = (const float4*)P.Wm1;
        float4 acc = {0.f, 0.f, 0.f, 0.f};
        #pragma unroll 4
        for (int ii = 0; ii < cnt; ++ii) {
            const float xv = xvE[ii];
            float4 w = ntload4(W4 + (size_t)(row0 + riE[ii]) * 256 + tid);
            acc.x += xv*w.x; acc.y += xv*w.y; acc.z += xv*w.z; acc.w += xv*w.w;
        }
        ((float4*)P.part1)[(size_t)bid * 256 + tid] = acc;
    }
    grid.sync();

    // ============ Phase F: h1 = tanh(colsum(part1)+bm1); part2 = h1@Wm2 ====
    if (bid < 256) {
        const int j0 = bid * 4;
        const int jj = tid & 3, kg = tid >> 2;       // 64 k-groups x 4 cols
        float sum = 0.f;
        for (int k = kg; k < NBLK; k += 64) sum += P.part1[(size_t)k * 1024 + j0 + jj];
        scratch[tid] = sum;
        __syncthreads();
        for (int off = 32; off > 0; off >>= 1) {
            if (kg < off) scratch[tid] += scratch[tid + off * 4];
            __syncthreads();
        }
        if (tid < 4) hsvF[tid] = tanhf(scratch[tid] + P.bm1[j0 + tid]);
        __syncthreads();
        const float4* W4 = (const float4*)P.Wm2;
        float4 acc = {0.f, 0.f, 0.f, 0.f};
        #pragma unroll
        for (int i = 0; i < 4; ++i) {
            const float xv = hsvF[i];
            float4 w = ntload4(W4 + (size_t)(j0 + i) * 256 + tid);
            acc.x += xv*w.x; acc.y += xv*w.y; acc.z += xv*w.z; acc.w += xv*w.w;
        }
        ((float4*)P.part2)[(size_t)bid * 256 + tid] = acc;
    }
    grid.sync();

    // ============ Phase G: h2 = tanh(colsum(part2)+bm2)  (blocks 0..15) ====
    if (bid < 16) {
        const int jj = tid & 63, kg = tid >> 6;
        const int j = bid * 64 + jj;
        float sum = 0.f;
        for (int k = kg; k < 256; k += 4) sum += P.part2[(size_t)k * 1024 + j];
        scratch[tid] = sum;
        __syncthreads();
        if (kg < 2) scratch[tid] += scratch[tid + 128];
        __syncthreads();
        if (kg == 0) P.h2[j] = tanhf(scratch[tid] + scratch[tid + 64] + P.bm2[j]);
    }
    grid.sync();

    // ============ Phase H: out = h2 . Wm3 + bm3  (block 0) =================
    if (bid == 0) {
        float4 a  = ((const float4*)P.h2)[tid];
        float4 ww = ((const float4*)P.Wm3)[tid];
        scratch[tid] = dot4(a, ww);
        __syncthreads();
        for (int off = 128; off > 0; off >>= 1) {
            if (tid < off) scratch[tid] += scratch[tid + off];
            __syncthreads();
        }
        if (tid == 0) P.out[0] = scratch[0] + P.bm3[0];
    }
}

// ===========================================================================
// PATH 2 (fallback if cooperative launch is rejected): round-8 9-kernel chain
// ===========================================================================
__global__ void gemv_rows(const float* __restrict__ A, const float* __restrict__ x,
                          float* __restrict__ y, int C4) {
    const int tid = threadIdx.x;
    const int row = blockIdx.x;
    const float4* A4 = (const float4*)A + (size_t)row * C4;
    const float4* X4 = (const float4*)x;
    float acc = 0.f;
    #pragma unroll 4
    for (int p = tid; p < C4; p += 256) acc += dot4(ntload4(A4 + p), X4[p]);
    acc = wred(acc);
    __shared__ float s[4];
    if ((tid & 63) == 0) s[tid >> 6] = acc;
    __syncthreads();
    if (tid == 0) y[row] = s[0] + s[1] + s[2] + s[3];
}

__global__ void gemv_T_p1(const float* __restrict__ T, const float* __restrict__ Ze,
                          const float* __restrict__ X, const float* __restrict__ W1,
                          float* __restrict__ P1) {
    const int tid = threadIdx.x;
    const int row = blockIdx.x;
    const float4* A4 = (const float4*)T + (size_t)row * (N_EDGES / 4);
    const float4* X4 = (const float4*)Ze;
    float acc = 0.f;
    #pragma unroll 4
    for (int p = tid; p < N_EDGES / 4; p += 256) acc += dot4(ntload4(A4 + p), X4[p]);
    acc = wred(acc);
    __shared__ float s[4];
    if ((tid & 63) == 0) s[tid >> 6] = acc;
    __syncthreads();
    if (tid < 16) {
        const float tze = s[0] + s[1] + s[2] + s[3];
        P1[(row >> 2) * 64 + tid * 4 + (row & 3)] = X[row] * W1[tid] + tze * W1[16 + tid];
    }
}

__global__ __launch_bounds__(256) void adjmul_lds(
        const float* __restrict__ A, const float* __restrict__ P,
        const float* __restrict__ bias, const float* __restrict__ W2,
        float* __restrict__ outp, int fuse_p2) {
    __shared__ float As[8][2052];
    __shared__ float hs[8][16];
    const int tid = threadIdx.x;
    const int row0 = blockIdx.x * 8;
    const float4* Ag = (const float4*)A;
    #pragma unroll
    for (int r = 0; r < 8; ++r) {
        float4 v0 = ntload4(Ag + (size_t)(row0 + r) * 512 + tid);
        float4 v1 = ntload4(Ag + (size_t)(row0 + r) * 512 + 256 + tid);
        *(float4*)&As[r][tid * 4] = v0;
        *(float4*)&As[r][1024 + tid * 4] = v1;
    }
    __syncthreads();
    const int row = tid >> 5, p = tid & 31;
    const float4* P4 = (const float4*)P;
    float acc[16];
    #pragma unroll
    for (int c = 0; c < 16; ++c) acc[c] = 0.f;
    #pragma unroll 2
    for (int it = 0; it < 16; ++it) {
        const int k4 = it * 32 + p;
        float4 a = *(const float4*)&As[row][k4 * 4];
        const float4* Pr = P4 + (size_t)k4 * 16;
        #pragma unroll
        for (int c = 0; c < 16; ++c) acc[c] += dot4(a, Pr[c]);
    }
    #pragma unroll
    for (int c = 0; c < 16; ++c) {
        float v = acc[c];
        v += __shfl_xor(v, 1);  v += __shfl_xor(v, 2);  v += __shfl_xor(v, 4);
        v += __shfl_xor(v, 8);  v += __shfl_xor(v, 16);
        acc[c] = v;
    }
    if (fuse_p2) {
        if (p == 0) {
            #pragma unroll
            for (int c = 0; c < 16; ++c) hs[row][c] = fmaxf(acc[c] + bias[c], 0.f);
        }
        __syncthreads();
        if (tid < 128) {
            const int k = tid >> 4, c2 = tid & 15;
            float sv = 0.f;
            #pragma unroll
            for (int h = 0; h < 16; ++h) sv += hs[k][h] * W2[h * 16 + c2];
            const int kg = row0 + k;
            outp[(kg >> 2) * 64 + c2 * 4 + (kg & 3)] = sv;
        }
    } else {
        if (p == 0) {
            const int grow = row0 + row;
            #pragma unroll
            for (int c = 0; c < 16; ++c) outp[grow * 16 + c] = acc[c] + bias[c];
        }
    }
}

__global__ void prep_kernel(const float* __restrict__ flag, const float* __restrict__ cost,
                            int* __restrict__ src, float* __restrict__ lse) {
    __shared__ int   si[256];
    __shared__ float sf[256];
    const int tid = threadIdx.x;
    const int base = tid * 16;
    const float4* F4 = (const float4*)flag;
    float fv[16];
    #pragma unroll
    for (int q = 0; q < 4; ++q) {
        float4 v = F4[tid * 4 + q];
        fv[q*4+0] = v.x; fv[q*4+1] = v.y; fv[q*4+2] = v.z; fv[q*4+3] = v.w;
    }
    int f[16]; int local = 0;
    #pragma unroll
    for (int e = 0; e < 16; ++e) { f[e] = fv[e] > 0.5f ? 1 : 0; local += f[e]; }
    si[tid] = local;
    __syncthreads();
    #pragma unroll
    for (int off = 1; off < 256; off <<= 1) {
        int t = si[tid];
        if (tid >= off) t += si[tid - off];
        __syncthreads();
        si[tid] = t;
        __syncthreads();
    }
    int run = si[tid] - local;
    #pragma unroll
    for (int e = 0; e < 16; ++e) {
        run += f[e];
        int v = run - 1;
        v = v < 0 ? 0 : (v > N_NODES - 1 ? N_NODES - 1 : v);
        src[base + e] = v;
    }
    const float4* C4v = (const float4*)cost;
    float4 cv = C4v[tid*4+0], cw = C4v[tid*4+1];
    float4 cy = C4v[tid*4+2], cz = C4v[tid*4+3];
    float m = fmaxf(fmaxf(fmaxf(cv.x,cv.y), fmaxf(cv.z,cv.w)),
                    fmaxf(fmaxf(cw.x,cw.y), fmaxf(cw.z,cw.w)));
    m = fmaxf(m, fmaxf(fmaxf(fmaxf(cy.x,cy.y), fmaxf(cy.z,cy.w)),
                       fmaxf(fmaxf(cz.x,cz.y), fmaxf(cz.z,cz.w))));
    sf[tid] = m;
    __syncthreads();
    for (int off = 128; off > 0; off >>= 1) {
        if (tid < off) sf[tid] = fmaxf(sf[tid], sf[tid + off]);
        __syncthreads();
    }
    const float M = sf[0];
    __syncthreads();
    float sum = expf(cv.x-M)+expf(cv.y-M)+expf(cv.z-M)+expf(cv.w-M)
              + expf(cw.x-M)+expf(cw.y-M)+expf(cw.z-M)+expf(cw.w-M)
              + expf(cy.x-M)+expf(cy.y-M)+expf(cy.z-M)+expf(cy.w-M)
              + expf(cz.x-M)+expf(cz.y-M)+expf(cz.z-M)+expf(cz.w-M);
    sf[tid] = sum;
    __syncthreads();
    for (int off = 128; off > 0; off >>= 1) {
        if (tid < off) sf[tid] += sf[tid + off];
        __syncthreads();
    }
    if (tid == 0) lse[0] = M + logf(sf[0]);
}

__global__ void gemv_obs_wm1(const float* __restrict__ W, const float* __restrict__ cost,
                             const float* __restrict__ flag, const float* __restrict__ dual,
                             const float* __restrict__ emb, const int* __restrict__ src,
                             const float* __restrict__ lse, float* __restrict__ partial) {
    const int tid = threadIdx.x;
    const int row0 = blockIdx.x * ROWS1;
    __shared__ float xs[128];
    __shared__ float xv_c[128];
    __shared__ int   ri_c[128];
    __shared__ int   wcnt[2];
    __shared__ int   cnt_s;
    if (tid < ROWS1) {
        const int i_din = row0 + tid;
        const int i = i_din / 19;
        const int c = i_din - i * 19;
        const float fl = flag[i];
        float v;
        if (c == 0)      v = cost[i] - lse[0];
        else if (c == 1) v = fl;
        else if (c == 2) v = (fl > 0.5f) ? dual[src[i]] : 1.0f;
        else             v = (fl > 0.5f) ? emb[src[i] * 16 + (c - 3)] : 0.0f;
        xs[tid] = v;
    }
    __syncthreads();
    const bool pred = (tid < ROWS1) && (xs[tid] != 0.0f);
    const unsigned long long mask = __ballot(pred);
    const int lane = tid & 63, wid = tid >> 6;
    const int wpre = __popcll(mask & ((1ull << lane) - 1ull));
    if (lane == 0 && wid < 2) wcnt[wid] = __popcll(mask);
    __syncthreads();
    if (tid == 0) cnt_s = wcnt[0] + wcnt[1];
    __syncthreads();
    if (pred) {
        const int idx = (wid == 0 ? 0 : wcnt[0]) + wpre;
        xv_c[idx] = xs[tid];
        ri_c[idx] = tid;
    }
    __syncthreads();
    const int cnt = cnt_s;
    const float4* W4 = (const float4*)W;
    float4 acc = {0.f, 0.f, 0.f, 0.f};
    #pragma unroll 4
    for (int ii = 0; ii < cnt; ++ii) {
        const float xv = xv_c[ii];
        float4 w = ntload4(W4 + (size_t)(row0 + ri_c[ii]) * 256 + tid);
        acc.x += xv*w.x; acc.y += xv*w.y; acc.z += xv*w.z; acc.w += xv*w.w;
    }
    ((float4*)partial)[(size_t)blockIdx.x * 256 + tid] = acc;
}

__global__ void wm2_fused(const float* __restrict__ part1, const float* __restrict__ bm1,
                          const float* __restrict__ Wm2, float* __restrict__ part2) {
    const int tid = threadIdx.x;
    const int j0 = blockIdx.x * ROWS2;
    const int jj = tid & 3, kg = tid >> 2;
    float sum = 0.f;
    for (int k = kg; k < NBLK; k += 64) sum += part1[(size_t)k * 1024 + j0 + jj];
    __shared__ float s[256];
    __shared__ float hsv[4];
    s[tid] = sum;
    __syncthreads();
    for (int off = 32; off > 0; off >>= 1) {
        if (kg < off) s[tid] += s[tid + off * 4];
        __syncthreads();
    }
    if (tid < 4) hsv[tid] = tanhf(s[tid] + bm1[j0 + tid]);
    __syncthreads();
    const float4* W4 = (const float4*)Wm2;
    float4 acc = {0.f, 0.f, 0.f, 0.f};
    #pragma unroll
    for (int i = 0; i < ROWS2; ++i) {
        const float xv = hsv[i];
        float4 w = ntload4(W4 + (size_t)(j0 + i) * 256 + tid);
        acc.x += xv*w.x; acc.y += xv*w.y; acc.z += xv*w.z; acc.w += xv*w.w;
    }
    ((float4*)part2)[(size_t)blockIdx.x * 256 + tid] = acc;
}

__global__ void reduce_cols(const float* __restrict__ partial, int nchunk,
                            const float* __restrict__ bias, float* __restrict__ out,
                            int do_tanh) {
    const int tid = threadIdx.x;
    const int jj = tid & 63, kg = tid >> 6;
    const int j = blockIdx.x * 64 + jj;
    float sum = 0.f;
    for (int k = kg; k < nchunk; k += 4) sum += partial[(size_t)k * 1024 + j];
    __shared__ float s[256];
    s[tid] = sum;
    __syncthreads();
    if (kg < 2) s[tid] += s[tid + 128];
    __syncthreads();
    if (kg == 0) {
        float v = s[tid] + s[tid + 64] + bias[j];
        out[j] = do_tanh ? tanhf(v) : v;
    }
}

__global__ void final_dot(const float* __restrict__ h, const float* __restrict__ w,
                          const float* __restrict__ b, float* __restrict__ out) {
    const int tid = threadIdx.x;
    float4 a  = ((const float4*)h)[tid];
    float4 ww = ((const float4*)w)[tid];
    float acc = dot4(a, ww);
    __shared__ float s[256];
    s[tid] = acc;
    __syncthreads();
    for (int off = 128; off > 0; off >>= 1) {
        if (tid < off) s[tid] += s[tid + off];
        __syncthreads();
    }
    if (tid == 0) out[0] = s[0] + b[0];
}

// ---------------------------------------------------------------------------
extern "C" void kernel_launch(void* const* d_in, const int* in_sizes, int n_in,
                              void* d_out, int out_size, void* d_ws, size_t ws_size,
                              hipStream_t stream) {
    char* ws = (char*)d_ws;
    KP kp;
    kp.X     = (const float*)d_in[0];
    kp.Z     = (const float*)d_in[1];
    kp.adj_e = (const float*)d_in[2];
    kp.adj_v = (const float*)d_in[3];
    kp.T     = (const float*)d_in[4];
    kp.cost  = (const float*)d_in[5];
    kp.flag  = (const float*)d_in[6];
    kp.dual  = (const float*)d_in[7];
    kp.W1    = (const float*)d_in[8];
    kp.b1    = (const float*)d_in[9];
    kp.W2    = (const float*)d_in[10];
    kp.b2    = (const float*)d_in[11];
    kp.Wm1   = (const float*)d_in[12];
    kp.bm1   = (const float*)d_in[13];
    kp.Wm2   = (const float*)d_in[14];
    kp.bm2   = (const float*)d_in[15];
    kp.Wm3   = (const float*)d_in[16];
    kp.bm3   = (const float*)d_in[17];
    kp.out   = (float*)d_out;
    // workspace carve-up (256B aligned, gap-free; total ~5.7 MB)
    kp.Ze    = (float*)(ws + 0);          //  16 KB
    kp.P1    = (float*)(ws + 16384);      // 128 KB tile
    kp.P2    = (float*)(ws + 147456);     // 128 KB tile
    kp.emb   = (float*)(ws + 278528);     // 128 KB
    kp.src   = (int*)  (ws + 409600);     //  16 KB
    kp.lse   = (float*)(ws + 425984);     // 256 B
    kp.part1 = (float*)(ws + 426240);     //   4 MB [1024][1024]
    kp.part2 = (float*)(ws + 4620544);    //   1 MB [256][1024]
    kp.h2    = (float*)(ws + 5669120);    //   4 KB

    void* kargs[] = { (void*)&kp };
    hipError_t err = hipLaunchCooperativeKernel(reinterpret_cast<void*>(&fused_all),
                                                dim3(NBLK), dim3(256), kargs, 0, stream);
    if (err != hipSuccess) {
        // Deterministic fallback: proven 9-kernel chain (round-8, passed).
        prep_kernel<<<1, 256, 0, stream>>>(kp.flag, kp.cost, kp.src, kp.lse);
        gemv_rows<<<N_EDGES, 256, 0, stream>>>(kp.adj_e, kp.Z, kp.Ze, N_EDGES / 4);
        gemv_T_p1<<<N_NODES, 256, 0, stream>>>(kp.T, kp.Ze, kp.X, kp.W1, kp.P1);
        adjmul_lds<<<N_NODES / 8, 256, 0, stream>>>(kp.adj_v, kp.P1, kp.b1, kp.W2, kp.P2, 1);
        adjmul_lds<<<N_NODES / 8, 256, 0, stream>>>(kp.adj_v, kp.P2, kp.b2, kp.W2, kp.emb, 0);
        gemv_obs_wm1<<<NBLK, 256, 0, stream>>>(kp.Wm1, kp.cost, kp.flag, kp.dual,
                                               kp.emb, kp.src, kp.lse, kp.part1);
        wm2_fused<<<NCHUNK2, 256, 0, stream>>>(kp.part1, kp.bm1, kp.Wm2, kp.part2);
        reduce_cols<<<16, 256, 0, stream>>>(kp.part2, NCHUNK2, kp.bm2, kp.h2, 1);
        final_dot<<<1, 256, 0, stream>>>(kp.h2, kp.Wm3, kp.bm3, kp.out);
    }
}